// Round 14
// baseline (1010.622 us; speedup 1.0000x reference)
//
#include <hip/hip_runtime.h>

#define NNODES 100000
#define NGRAPHS 512
#define D 128
#define OUTC 64
#define NEDGES 1600000
#define SCAN_NB ((NNODES + 1 + 1023) / 1024)  // 98 blocks

// ---------------- CSR build ----------------

__global__ void k_deg(const int* __restrict__ dst, int* __restrict__ deg, int E) {
    int e = blockIdx.x * 256 + threadIdx.x;
    if (e < E) atomicAdd(&deg[dst[e]], 1);
}

// hierarchical scan: per-block exclusive scan + block sums
__global__ __launch_bounds__(1024) void k_scan1(const int* __restrict__ deg,
                                                int* __restrict__ off,
                                                int* __restrict__ bsum) {
    __shared__ int sm[1024];
    int t = threadIdx.x;
    int i = blockIdx.x * 1024 + t;
    int v = (i < NNODES) ? deg[i] : 0;  // virtual element NNODES = 0
    sm[t] = v;
    __syncthreads();
    #pragma unroll
    for (int ofs = 1; ofs < 1024; ofs <<= 1) {
        int add = (t >= ofs) ? sm[t - ofs] : 0;
        __syncthreads();
        sm[t] += add;
        __syncthreads();
    }
    if (i <= NNODES) off[i] = sm[t] - v;  // block-local exclusive
    if (t == 1023) bsum[blockIdx.x] = sm[1023];
}

__global__ __launch_bounds__(128) void k_scan2(int* __restrict__ bsum) {
    __shared__ int sm[128];
    int t = threadIdx.x;
    int v = (t < SCAN_NB) ? bsum[t] : 0;
    sm[t] = v;
    __syncthreads();
    #pragma unroll
    for (int ofs = 1; ofs < 128; ofs <<= 1) {
        int add = (t >= ofs) ? sm[t - ofs] : 0;
        __syncthreads();
        sm[t] += add;
        __syncthreads();
    }
    if (t < SCAN_NB) bsum[t] = sm[t] - v;  // exclusive block offsets
}

__global__ __launch_bounds__(1024) void k_scan3(int* __restrict__ off,
                                                const int* __restrict__ bsum) {
    int i = blockIdx.x * 1024 + threadIdx.x;
    if (i <= NNODES) off[i] += bsum[blockIdx.x];
}

__global__ void k_fill(const int* __restrict__ src, const int* __restrict__ dst,
                       const int* __restrict__ off, int* __restrict__ cur,
                       int* __restrict__ csr, int E) {
    int e = blockIdx.x * 256 + threadIdx.x;
    if (e < E) {
        int d = dst[e];
        int p = off[d] + atomicAdd(&cur[d], 1);
        csr[p] = src[e];
    }
}

// ------------- fused GIN layer: h = relu((x + sum_nbr x) @ W + b) -----------
// block = 256 threads, tile = 32 nodes. LDS 33 KB -> 4 blocks/CU (was 3 at
// 64-node tile): more resident gather streams + phase1/phase2 overlap.
// Phase 1 (R12-verified gather): thread = (node ln = p*8 + t>>5, cols
//   c=(t&31)*4); 32 threads/row -> coalesced 512B row reads; 8-deep MLP,
//   results straight into xs LDS.
// Phase 2 (R5/R12-verified GEMM pattern): thread = 4 nodes x 4 cols,
//   acc[4][4]=16 regs, Wl stride 128 conflict-free, named-field accesses.

__global__ __launch_bounds__(256, 4) void k_layer(
    const float* __restrict__ xin, const int* __restrict__ off,
    const int* __restrict__ csr, const float* __restrict__ W,
    const float* __restrict__ bias, float* __restrict__ hout) {
    __shared__ float xs[32 * 132];  // 16.9 KB, padded stride
    __shared__ float Wl[32 * 128];  // 16 KB, quarter of W

    int t = threadIdx.x;
    int n0 = blockIdx.x * 32;
    int c = (t & 31) << 2;  // float offset in row
    int nl = t >> 5;        // 0..7

    // ---- Phase 1: gather into xs ----
    for (int p = 0; p < 4; ++p) {
        int ln = p * 8 + nl;  // 0..31
        int n = n0 + ln;
        if (n > NNODES - 1) n = NNODES - 1;  // clamp tail (no early return: barriers)

        float4 acc = *(const float4*)(xin + (size_t)n * D + c);  // self term
        int o0 = off[n], o1 = off[n + 1];
        for (int j = o0; j < o1; j += 8) {
            int idx[8];
            float m[8];
            #pragma unroll
            for (int k = 0; k < 8; ++k) {
                int jj = j + k;
                bool ok = jj < o1;
                idx[k] = ok ? csr[jj] : n;  // clamp: valid addr
                m[k] = ok ? 1.f : 0.f;
            }
            float4 v[8];
            #pragma unroll
            for (int k = 0; k < 8; ++k)
                v[k] = *(const float4*)(xin + (size_t)idx[k] * D + c);
            #pragma unroll
            for (int k = 0; k < 8; ++k) {
                acc.x = fmaf(v[k].x, m[k], acc.x);
                acc.y = fmaf(v[k].y, m[k], acc.y);
                acc.z = fmaf(v[k].z, m[k], acc.z);
                acc.w = fmaf(v[k].w, m[k], acc.w);
            }
        }
        *(float4*)(xs + ln * 132 + c) = acc;
    }

    // ---- Phase 2: GEMM ----
    int cg = t & 31;  // 4-col group
    int ng = t >> 5;  // node group of 4: nodes ng*4..ng*4+3
    float4 bv = *(const float4*)(bias + cg * 4);
    float acc[4][4];
    #pragma unroll
    for (int i = 0; i < 4; ++i) {
        acc[i][0] = bv.x; acc[i][1] = bv.y; acc[i][2] = bv.z; acc[i][3] = bv.w;
    }

    for (int q = 0; q < 4; ++q) {
        __syncthreads();  // q==0: xs ready; q>0: previous Wl reads done
        for (int i = t; i < 32 * 32; i += 256) {
            int r = i >> 5, c4 = i & 31;
            *(float4*)(Wl + r * 128 + c4 * 4) =
                *(const float4*)(W + (size_t)(q * 32 + r) * D + c4 * 4);
        }
        __syncthreads();
        #pragma unroll
        for (int k4 = 0; k4 < 8; ++k4) {
            float4 w0 = *(const float4*)(Wl + (k4 * 4 + 0) * 128 + cg * 4);
            float4 w1 = *(const float4*)(Wl + (k4 * 4 + 1) * 128 + cg * 4);
            float4 w2 = *(const float4*)(Wl + (k4 * 4 + 2) * 128 + cg * 4);
            float4 w3 = *(const float4*)(Wl + (k4 * 4 + 3) * 128 + cg * 4);
            #pragma unroll
            for (int i = 0; i < 4; ++i) {
                float4 xv = *(const float4*)(xs + (ng * 4 + i) * 132 + q * 32 + k4 * 4);
                acc[i][0] += xv.x * w0.x + xv.y * w1.x + xv.z * w2.x + xv.w * w3.x;
                acc[i][1] += xv.x * w0.y + xv.y * w1.y + xv.z * w2.y + xv.w * w3.y;
                acc[i][2] += xv.x * w0.z + xv.y * w1.z + xv.z * w2.z + xv.w * w3.z;
                acc[i][3] += xv.x * w0.w + xv.y * w1.w + xv.z * w2.w + xv.w * w3.w;
            }
        }
    }

    #pragma unroll
    for (int i = 0; i < 4; ++i) {
        int n = n0 + ng * 4 + i;
        if (n < NNODES) {
            float4 o;
            o.x = fmaxf(acc[i][0], 0.f);
            o.y = fmaxf(acc[i][1], 0.f);
            o.z = fmaxf(acc[i][2], 0.f);
            o.w = fmaxf(acc[i][3], 0.f);
            *(float4*)(hout + (size_t)n * D + cg * 4) = o;
        }
    }
}

// ---------------- graph offsets from sorted batch ----------------

__global__ void k_goff(const int* __restrict__ batch, int* __restrict__ goff, int N) {
    int i = blockIdx.x * 256 + threadIdx.x;
    if (i >= N) return;
    int b = batch[i];
    if (i == 0) {
        for (int g = 0; g <= b; ++g) goff[g] = 0;
    } else {
        int p = batch[i - 1];
        for (int g = p + 1; g <= b; ++g) goff[g] = i;
    }
    if (i == N - 1) {
        for (int g = b + 1; g <= NGRAPHS; ++g) goff[g] = N;
    }
}

// ---------------- mean pool: one block per graph ----------------

__global__ __launch_bounds__(128) void k_pool(const float* __restrict__ h,
                                              const int* __restrict__ goff,
                                              float* __restrict__ pooled) {
    int g = blockIdx.x, c = threadIdx.x;
    int s = goff[g], e = goff[g + 1];
    float a = 0.f;
    int n = s;
    for (; n + 4 <= e; n += 4) {
        float v0 = h[(size_t)(n + 0) * D + c];
        float v1 = h[(size_t)(n + 1) * D + c];
        float v2 = h[(size_t)(n + 2) * D + c];
        float v3 = h[(size_t)(n + 3) * D + c];
        a += (v0 + v1) + (v2 + v3);
    }
    for (; n < e; ++n) a += h[(size_t)n * D + c];
    pooled[(size_t)g * D + c] = a / fmaxf((float)(e - s), 1.f);
}

// ---------------- final FC ----------------

__global__ __launch_bounds__(64) void k_fc(const float* __restrict__ pooled,
                                           const float* __restrict__ Wfc,
                                           const float* __restrict__ bfc,
                                           float* __restrict__ out) {
    __shared__ float row[128];
    int g = blockIdx.x, o = threadIdx.x;
    row[o] = pooled[(size_t)g * D + o];
    row[o + 64] = pooled[(size_t)g * D + o + 64];
    __syncthreads();
    float a = bfc[o];
    #pragma unroll 8
    for (int k = 0; k < 128; ++k) a += row[k] * Wfc[k * OUTC + o];
    out[(size_t)g * OUTC + o] = a;
}

// ---------------- launch ----------------

extern "C" void kernel_launch(void* const* d_in, const int* in_sizes, int n_in,
                              void* d_out, int out_size, void* d_ws, size_t ws_size,
                              hipStream_t stream) {
    const float* x = (const float*)d_in[0];
    const int* ei = (const int*)d_in[1];
    const int* batch = (const int*)d_in[2];
    const float* W1 = (const float*)d_in[3];
    const float* b1 = (const float*)d_in[4];
    const float* W2 = (const float*)d_in[5];
    const float* b2 = (const float*)d_in[6];
    const float* W3 = (const float*)d_in[7];
    const float* b3 = (const float*)d_in[8];
    const float* Wfc = (const float*)d_in[9];
    const float* bfc = (const float*)d_in[10];
    float* out = (float*)d_out;

    const int* src = ei;           // edge_index[0]
    const int* dst = ei + NEDGES;  // edge_index[1]

    char* ws = (char*)d_ws;
    size_t P = 0;
    auto alloc = [&](size_t bytes) {
        size_t r = P;
        P += (bytes + 255) & ~(size_t)255;
        return r;
    };
    int* off = (int*)(ws + alloc((NNODES + 2) * 4));
    int* deg = (int*)(ws + alloc(NNODES * 4));
    int* cur = (int*)(ws + alloc(NNODES * 4));
    int* bsum = (int*)(ws + alloc(SCAN_NB * 4));
    int* csr = (int*)(ws + alloc((size_t)(NEDGES + 64) * 4));  // +pad for masked reads
    float* bufA = (float*)(ws + alloc((size_t)NNODES * D * 4));
    float* bufB = (float*)(ws + alloc((size_t)NNODES * D * 4));
    float* pooled = (float*)(ws + alloc((size_t)NGRAPHS * D * 4));
    int* goff = (int*)(ws + alloc((NGRAPHS + 1) * 4));

    hipMemsetAsync(deg, 0, NNODES * 4, stream);
    hipMemsetAsync(cur, 0, NNODES * 4, stream);

    k_deg<<<NEDGES / 256, 256, 0, stream>>>(dst, deg, NEDGES);
    k_scan1<<<SCAN_NB, 1024, 0, stream>>>(deg, off, bsum);
    k_scan2<<<1, 128, 0, stream>>>(bsum);
    k_scan3<<<SCAN_NB, 1024, 0, stream>>>(off, bsum);
    k_fill<<<NEDGES / 256, 256, 0, stream>>>(src, dst, off, cur, csr, NEDGES);
    k_goff<<<(NNODES + 255) / 256, 256, 0, stream>>>(batch, goff, NNODES);

    const int LAYER_GRID = (NNODES + 31) / 32;

    k_layer<<<LAYER_GRID, 256, 0, stream>>>(x, off, csr, W1, b1, bufA);
    k_layer<<<LAYER_GRID, 256, 0, stream>>>(bufA, off, csr, W2, b2, bufB);
    k_layer<<<LAYER_GRID, 256, 0, stream>>>(bufB, off, csr, W3, b3, bufA);

    k_pool<<<NGRAPHS, 128, 0, stream>>>(bufA, goff, pooled);
    k_fc<<<NGRAPHS, 64, 0, stream>>>(pooled, Wfc, bfc, out);
}

// Round 16
// 794.219 us; speedup vs baseline: 1.2725x; 1.2725x over previous
//
#include <hip/hip_runtime.h>

#define NNODES 100000
#define NGRAPHS 512
#define D 128
#define OUTC 64
#define NEDGES 1600000
#define SCAN_NB ((NNODES + 1 + 1023) / 1024)  // 98 blocks

// ---------------- CSR build ----------------

__global__ void k_deg(const int* __restrict__ dst, int* __restrict__ deg, int E) {
    int e = blockIdx.x * 256 + threadIdx.x;
    if (e < E) atomicAdd(&deg[dst[e]], 1);
}

// hierarchical scan: per-block exclusive scan + block sums
__global__ __launch_bounds__(1024) void k_scan1(const int* __restrict__ deg,
                                                int* __restrict__ off,
                                                int* __restrict__ bsum) {
    __shared__ int sm[1024];
    int t = threadIdx.x;
    int i = blockIdx.x * 1024 + t;
    int v = (i < NNODES) ? deg[i] : 0;  // virtual element NNODES = 0
    sm[t] = v;
    __syncthreads();
    #pragma unroll
    for (int ofs = 1; ofs < 1024; ofs <<= 1) {
        int add = (t >= ofs) ? sm[t - ofs] : 0;
        __syncthreads();
        sm[t] += add;
        __syncthreads();
    }
    if (i <= NNODES) off[i] = sm[t] - v;  // block-local exclusive
    if (t == 1023) bsum[blockIdx.x] = sm[1023];
}

__global__ __launch_bounds__(128) void k_scan2(int* __restrict__ bsum) {
    __shared__ int sm[128];
    int t = threadIdx.x;
    int v = (t < SCAN_NB) ? bsum[t] : 0;
    sm[t] = v;
    __syncthreads();
    #pragma unroll
    for (int ofs = 1; ofs < 128; ofs <<= 1) {
        int add = (t >= ofs) ? sm[t - ofs] : 0;
        __syncthreads();
        sm[t] += add;
        __syncthreads();
    }
    if (t < SCAN_NB) bsum[t] = sm[t] - v;  // exclusive block offsets
}

__global__ __launch_bounds__(1024) void k_scan3(int* __restrict__ off,
                                                const int* __restrict__ bsum) {
    int i = blockIdx.x * 1024 + threadIdx.x;
    if (i <= NNODES) off[i] += bsum[blockIdx.x];
}

__global__ void k_fill(const int* __restrict__ src, const int* __restrict__ dst,
                       const int* __restrict__ off, int* __restrict__ cur,
                       int* __restrict__ csr, int E) {
    int e = blockIdx.x * 256 + threadIdx.x;
    if (e < E) {
        int d = dst[e];
        int p = off[d] + atomicAdd(&cur[d], 1);
        csr[p] = src[e];
    }
}

// ------------- fused GIN layer: h = relu((x + sum_nbr x) @ W + b) -----------
// block = 256 threads, tile = 64 nodes (R13-verified locality).
// LDS = xs only (33 KB) -> 4 blocks/CU; W is read through L1/L2 (64 KB,
// shared by all blocks -> L1-resident after first touch). Single barrier
// between phases: co-resident blocks overlap gather (mem) with GEMM (VALU).
// Phase 1 (R12-verified gather): thread = (node, 16B col slice), 32
//   threads/row -> coalesced 512B row reads; 8-deep MLP.
// Phase 2 (R5-verified tile): thread = 8 nodes x 4 cols, acc[8][4]=32 regs,
//   named-field accesses only (no address-taken indexing).

__global__ __launch_bounds__(256, 4) void k_layer(
    const float* __restrict__ xin, const int* __restrict__ off,
    const int* __restrict__ csr, const float* __restrict__ W,
    const float* __restrict__ bias, float* __restrict__ hout) {
    __shared__ float xs[64 * 132];  // 33 KB, padded stride

    int t = threadIdx.x;
    int n0 = blockIdx.x * 64;
    int c = (t & 31) << 2;  // float offset in row
    int nl = t >> 5;        // 0..7

    // ---- Phase 1: gather into xs ----
    for (int p = 0; p < 8; ++p) {
        int ln = p * 8 + nl;  // 0..63
        int n = n0 + ln;
        if (n > NNODES - 1) n = NNODES - 1;  // clamp tail (no early return: barrier)

        float4 acc = *(const float4*)(xin + (size_t)n * D + c);  // self term
        int o0 = off[n], o1 = off[n + 1];
        for (int j = o0; j < o1; j += 8) {
            int idx[8];
            float m[8];
            #pragma unroll
            for (int k = 0; k < 8; ++k) {
                int jj = j + k;
                bool ok = jj < o1;
                idx[k] = ok ? csr[jj] : n;  // clamp: valid addr
                m[k] = ok ? 1.f : 0.f;
            }
            float4 v[8];
            #pragma unroll
            for (int k = 0; k < 8; ++k)
                v[k] = *(const float4*)(xin + (size_t)idx[k] * D + c);
            #pragma unroll
            for (int k = 0; k < 8; ++k) {
                acc.x = fmaf(v[k].x, m[k], acc.x);
                acc.y = fmaf(v[k].y, m[k], acc.y);
                acc.z = fmaf(v[k].z, m[k], acc.z);
                acc.w = fmaf(v[k].w, m[k], acc.w);
            }
        }
        *(float4*)(xs + ln * 132 + c) = acc;
    }

    __syncthreads();  // xs ready; only barrier in the kernel

    // ---- Phase 2: GEMM (W via L1/L2) ----
    int cg = t & 31;  // 4-col group
    int ng = t >> 5;  // node group of 8
    float4 bv = *(const float4*)(bias + cg * 4);
    float acc[8][4];
    #pragma unroll
    for (int i = 0; i < 8; ++i) {
        acc[i][0] = bv.x; acc[i][1] = bv.y; acc[i][2] = bv.z; acc[i][3] = bv.w;
    }

    #pragma unroll 4
    for (int k4 = 0; k4 < 32; ++k4) {
        float4 w0 = *(const float4*)(W + (size_t)(k4 * 4 + 0) * D + cg * 4);
        float4 w1 = *(const float4*)(W + (size_t)(k4 * 4 + 1) * D + cg * 4);
        float4 w2 = *(const float4*)(W + (size_t)(k4 * 4 + 2) * D + cg * 4);
        float4 w3 = *(const float4*)(W + (size_t)(k4 * 4 + 3) * D + cg * 4);
        #pragma unroll
        for (int i = 0; i < 8; ++i) {
            float4 xv = *(const float4*)(xs + (ng * 8 + i) * 132 + k4 * 4);
            acc[i][0] += xv.x * w0.x + xv.y * w1.x + xv.z * w2.x + xv.w * w3.x;
            acc[i][1] += xv.x * w0.y + xv.y * w1.y + xv.z * w2.y + xv.w * w3.y;
            acc[i][2] += xv.x * w0.z + xv.y * w1.z + xv.z * w2.z + xv.w * w3.z;
            acc[i][3] += xv.x * w0.w + xv.y * w1.w + xv.z * w2.w + xv.w * w3.w;
        }
    }

    #pragma unroll
    for (int i = 0; i < 8; ++i) {
        int n = n0 + ng * 8 + i;
        if (n < NNODES) {
            float4 o;
            o.x = fmaxf(acc[i][0], 0.f);
            o.y = fmaxf(acc[i][1], 0.f);
            o.z = fmaxf(acc[i][2], 0.f);
            o.w = fmaxf(acc[i][3], 0.f);
            *(float4*)(hout + (size_t)n * D + cg * 4) = o;
        }
    }
}

// ---------------- graph offsets from sorted batch ----------------

__global__ void k_goff(const int* __restrict__ batch, int* __restrict__ goff, int N) {
    int i = blockIdx.x * 256 + threadIdx.x;
    if (i >= N) return;
    int b = batch[i];
    if (i == 0) {
        for (int g = 0; g <= b; ++g) goff[g] = 0;
    } else {
        int p = batch[i - 1];
        for (int g = p + 1; g <= b; ++g) goff[g] = i;
    }
    if (i == N - 1) {
        for (int g = b + 1; g <= NGRAPHS; ++g) goff[g] = N;
    }
}

// ---------------- mean pool: one block per graph ----------------

__global__ __launch_bounds__(128) void k_pool(const float* __restrict__ h,
                                              const int* __restrict__ goff,
                                              float* __restrict__ pooled) {
    int g = blockIdx.x, c = threadIdx.x;
    int s = goff[g], e = goff[g + 1];
    float a = 0.f;
    int n = s;
    for (; n + 4 <= e; n += 4) {
        float v0 = h[(size_t)(n + 0) * D + c];
        float v1 = h[(size_t)(n + 1) * D + c];
        float v2 = h[(size_t)(n + 2) * D + c];
        float v3 = h[(size_t)(n + 3) * D + c];
        a += (v0 + v1) + (v2 + v3);
    }
    for (; n < e; ++n) a += h[(size_t)n * D + c];
    pooled[(size_t)g * D + c] = a / fmaxf((float)(e - s), 1.f);
}

// ---------------- final FC ----------------

__global__ __launch_bounds__(64) void k_fc(const float* __restrict__ pooled,
                                           const float* __restrict__ Wfc,
                                           const float* __restrict__ bfc,
                                           float* __restrict__ out) {
    __shared__ float row[128];
    int g = blockIdx.x, o = threadIdx.x;
    row[o] = pooled[(size_t)g * D + o];
    row[o + 64] = pooled[(size_t)g * D + o + 64];
    __syncthreads();
    float a = bfc[o];
    #pragma unroll 8
    for (int k = 0; k < 128; ++k) a += row[k] * Wfc[k * OUTC + o];
    out[(size_t)g * OUTC + o] = a;
}

// ---------------- launch ----------------

extern "C" void kernel_launch(void* const* d_in, const int* in_sizes, int n_in,
                              void* d_out, int out_size, void* d_ws, size_t ws_size,
                              hipStream_t stream) {
    const float* x = (const float*)d_in[0];
    const int* ei = (const int*)d_in[1];
    const int* batch = (const int*)d_in[2];
    const float* W1 = (const float*)d_in[3];
    const float* b1 = (const float*)d_in[4];
    const float* W2 = (const float*)d_in[5];
    const float* b2 = (const float*)d_in[6];
    const float* W3 = (const float*)d_in[7];
    const float* b3 = (const float*)d_in[8];
    const float* Wfc = (const float*)d_in[9];
    const float* bfc = (const float*)d_in[10];
    float* out = (float*)d_out;

    const int* src = ei;           // edge_index[0]
    const int* dst = ei + NEDGES;  // edge_index[1]

    char* ws = (char*)d_ws;
    size_t P = 0;
    auto alloc = [&](size_t bytes) {
        size_t r = P;
        P += (bytes + 255) & ~(size_t)255;
        return r;
    };
    int* off = (int*)(ws + alloc((NNODES + 2) * 4));
    int* deg = (int*)(ws + alloc(NNODES * 4));
    int* cur = (int*)(ws + alloc(NNODES * 4));
    int* bsum = (int*)(ws + alloc(SCAN_NB * 4));
    int* csr = (int*)(ws + alloc((size_t)(NEDGES + 64) * 4));  // +pad for masked reads
    float* bufA = (float*)(ws + alloc((size_t)NNODES * D * 4));
    float* bufB = (float*)(ws + alloc((size_t)NNODES * D * 4));
    float* pooled = (float*)(ws + alloc((size_t)NGRAPHS * D * 4));
    int* goff = (int*)(ws + alloc((NGRAPHS + 1) * 4));

    hipMemsetAsync(deg, 0, NNODES * 4, stream);
    hipMemsetAsync(cur, 0, NNODES * 4, stream);

    k_deg<<<NEDGES / 256, 256, 0, stream>>>(dst, deg, NEDGES);
    k_scan1<<<SCAN_NB, 1024, 0, stream>>>(deg, off, bsum);
    k_scan2<<<1, 128, 0, stream>>>(bsum);
    k_scan3<<<SCAN_NB, 1024, 0, stream>>>(off, bsum);
    k_fill<<<NEDGES / 256, 256, 0, stream>>>(src, dst, off, cur, csr, NEDGES);
    k_goff<<<(NNODES + 255) / 256, 256, 0, stream>>>(batch, goff, NNODES);

    const int LAYER_GRID = (NNODES + 63) / 64;

    k_layer<<<LAYER_GRID, 256, 0, stream>>>(x, off, csr, W1, b1, bufA);
    k_layer<<<LAYER_GRID, 256, 0, stream>>>(bufA, off, csr, W2, b2, bufB);
    k_layer<<<LAYER_GRID, 256, 0, stream>>>(bufB, off, csr, W3, b3, bufA);

    k_pool<<<NGRAPHS, 128, 0, stream>>>(bufA, goff, pooled);
    k_fc<<<NGRAPHS, 64, 0, stream>>>(pooled, Wfc, bfc, out);
}